// Round 5
// baseline (406.989 us; speedup 1.0000x reference)
//
#include <hip/hip_runtime.h>

#define FUSE_K 20
#define NCH 16

typedef unsigned short u16;
typedef u16 u16x8 __attribute__((ext_vector_type(8)));

// ---------- Pass 1: src_feat fp32 (M,16) -> bf16 (M,16) in d_ws ----------
// Each thread: read 8 floats (2x float4), write 8 bf16 (16 B). RNE rounding.
__global__ __launch_bounds__(256) void convert_bf16_kernel(
    const float4* __restrict__ src, u16x8* __restrict__ dst, int n8)
{
    int gid = blockIdx.x * blockDim.x + threadIdx.x;
    if (gid >= n8) return;
    float4 a = src[2 * gid];
    float4 b = src[2 * gid + 1];
    float f[8] = {a.x, a.y, a.z, a.w, b.x, b.y, b.z, b.w};
    u16x8 r;
#pragma unroll
    for (int j = 0; j < 8; ++j) {
        unsigned int bits = __builtin_bit_cast(unsigned int, f[j]);
        bits += 0x7FFFu + ((bits >> 16) & 1u);   // round-to-nearest-even
        r[j] = (u16)(bits >> 16);
    }
    dst[gid] = r;
}

// ---------- Pass 2: gather bf16 rows (32 B each), accumulate fp32 ----------
// Thread = (voxel, 8-channel half): wave = 32 voxels x 2 lanes; each vmem
// gather instruction covers 32 distinct 32 B segments.
__global__ __launch_bounds__(256) void gather_bf16_kernel(
    const int* __restrict__ invoxel_map,   // (N, FUSE_K) int32
    const u16* __restrict__ feat16,        // (M, 16) bf16
    float4* __restrict__ out4,             // (N, 4) float4
    int N)
{
    int gid = blockIdx.x * blockDim.x + threadIdx.x;
    if (gid >= N * 2) return;

    int n = gid >> 1;   // voxel
    int h = gid & 1;    // 8-channel half

    const int4* mrow = (const int4*)(invoxel_map + (size_t)n * FUSE_K);
    int idx[FUSE_K];
#pragma unroll
    for (int k = 0; k < FUSE_K / 4; ++k) {
        int4 t = mrow[k];
        idx[4 * k + 0] = t.x;
        idx[4 * k + 1] = t.y;
        idx[4 * k + 2] = t.z;
        idx[4 * k + 3] = t.w;
    }
    int first = idx[0];

    float s[8] = {0, 0, 0, 0, 0, 0, 0, 0};
#pragma unroll
    for (int k = 0; k < FUSE_K; ++k) {
        int a = (idx[k] == 0) ? first : idx[k];
        u16x8 v = *(const u16x8*)(feat16 + (size_t)a * NCH + h * 8);
#pragma unroll
        for (int j = 0; j < 8; ++j) {
            unsigned int bits = ((unsigned int)v[j]) << 16;
            s[j] += __builtin_bit_cast(float, bits);
        }
    }

    float4 r0, r1;
    r0.x = s[0] * (1.0f / FUSE_K); r0.y = s[1] * (1.0f / FUSE_K);
    r0.z = s[2] * (1.0f / FUSE_K); r0.w = s[3] * (1.0f / FUSE_K);
    r1.x = s[4] * (1.0f / FUSE_K); r1.y = s[5] * (1.0f / FUSE_K);
    r1.z = s[6] * (1.0f / FUSE_K); r1.w = s[7] * (1.0f / FUSE_K);
    // out4 index: row n occupies slots [4n, 4n+4); half h covers 4n+2h, 4n+2h+1
    out4[2 * (size_t)gid + 0] = r0;
    out4[2 * (size_t)gid + 1] = r1;
}

// ---------- Fallback (ws too small): round-3 fp32 gather ----------
__global__ __launch_bounds__(256) void gather_f32_kernel(
    const int* __restrict__ invoxel_map,
    const float4* __restrict__ src_feat4,
    float4* __restrict__ out4,
    int N)
{
    int gid = blockIdx.x * blockDim.x + threadIdx.x;
    if (gid >= N * 4) return;
    int n = gid >> 2;
    int q = gid & 3;
    const int4* mrow = (const int4*)(invoxel_map + (size_t)n * FUSE_K);
    int idx[FUSE_K];
#pragma unroll
    for (int k = 0; k < FUSE_K / 4; ++k) {
        int4 t = mrow[k];
        idx[4 * k + 0] = t.x; idx[4 * k + 1] = t.y;
        idx[4 * k + 2] = t.z; idx[4 * k + 3] = t.w;
    }
    int first = idx[0];
    float4 v[FUSE_K];
#pragma unroll
    for (int k = 0; k < FUSE_K; ++k) {
        int a = (idx[k] == 0) ? first : idx[k];
        v[k] = src_feat4[(size_t)a * 4 + q];
    }
    float sx = 0.f, sy = 0.f, sz = 0.f, sw = 0.f;
#pragma unroll
    for (int k = 0; k < FUSE_K; ++k) {
        sx += v[k].x; sy += v[k].y; sz += v[k].z; sw += v[k].w;
    }
    float4 r;
    r.x = sx * (1.0f / FUSE_K); r.y = sy * (1.0f / FUSE_K);
    r.z = sz * (1.0f / FUSE_K); r.w = sw * (1.0f / FUSE_K);
    out4[gid] = r;
}

extern "C" void kernel_launch(void* const* d_in, const int* in_sizes, int n_in,
                              void* d_out, int out_size, void* d_ws, size_t ws_size,
                              hipStream_t stream) {
    // d_in[0] = invoxel_xyz (unused)
    // d_in[1] = invoxel_map (int32), in_sizes[1] = N * FUSE_K
    // d_in[2] = src_feat    (float32, M x 16), in_sizes[2] = M * 16
    const int*   invoxel_map = (const int*)d_in[1];
    const float* src_feat    = (const float*)d_in[2];
    float4*      out4        = (float4*)d_out;

    int N = in_sizes[1] / FUSE_K;
    int M = in_sizes[2] / NCH;
    size_t need = (size_t)M * NCH * sizeof(u16);  // 64 MB bf16 table

    int block = 256;

    if (ws_size >= need) {
        u16* feat16 = (u16*)d_ws;
        int n8 = M * NCH / 8;
        convert_bf16_kernel<<<(n8 + block - 1) / block, block, 0, stream>>>(
            (const float4*)src_feat, (u16x8*)d_ws, n8);
        int total = N * 2;
        gather_bf16_kernel<<<(total + block - 1) / block, block, 0, stream>>>(
            invoxel_map, feat16, out4, N);
    } else {
        int total = N * 4;
        gather_f32_kernel<<<(total + block - 1) / block, block, 0, stream>>>(
            invoxel_map, (const float4*)src_feat, out4, N);
    }
}

// Round 6
// 381.640 us; speedup vs baseline: 1.0664x; 1.0664x over previous
//
#include <hip/hip_runtime.h>

#define FUSE_K 20
#define NCH 16

// FINAL: single-pass fp32 gather. Thread = (voxel, 4-channel group);
// wave = 16 voxels x 4 lanes -> each wave gather instruction covers 16
// distinct contiguous 64 B src_feat rows (1 segment-request per row, the
// minimum). Measured repeatedly at the random-64B-line service-rate wall:
// FETCH_SIZE = 1.26 GB (exactly minimal), ~3.4-3.5 TB/s fetch service,
// dur ~= FETCH/3.4TB/s. MLP probe (forced 20 outstanding dwordx4/thread)
// and granule probe (bf16 32B rows) both left duration unchanged ->
// line-rate-bound, not latency-, byte-, or compute-bound.
__global__ __launch_bounds__(256) void VoxelPooling_kernel(
    const int* __restrict__ invoxel_map,    // (N, FUSE_K) int32
    const float4* __restrict__ src_feat4,   // (M,16) float == (M,4) float4
    float4* __restrict__ out4,              // (N,16) float == (N,4) float4
    int N)
{
    int gid = blockIdx.x * blockDim.x + threadIdx.x;
    if (gid >= N * 4) return;

    int n = gid >> 2;   // voxel
    int q = gid & 3;    // float4-group within the 16-channel row

    const int4* mrow = (const int4*)(invoxel_map + (size_t)n * FUSE_K);

    int idx[FUSE_K];
#pragma unroll
    for (int k = 0; k < FUSE_K / 4; ++k) {
        int4 t = mrow[k];
        idx[4 * k + 0] = t.x;
        idx[4 * k + 1] = t.y;
        idx[4 * k + 2] = t.z;
        idx[4 * k + 3] = t.w;
    }

    int first = idx[0];

    float4 v[FUSE_K];
#pragma unroll
    for (int k = 0; k < FUSE_K; ++k) {
        int a = (idx[k] == 0) ? first : idx[k];
        v[k] = src_feat4[(size_t)a * 4 + q];
    }

    float sx = 0.f, sy = 0.f, sz = 0.f, sw = 0.f;
#pragma unroll
    for (int k = 0; k < FUSE_K; ++k) {
        sx += v[k].x; sy += v[k].y; sz += v[k].z; sw += v[k].w;
    }

    float4 r;
    r.x = sx * (1.0f / FUSE_K);
    r.y = sy * (1.0f / FUSE_K);
    r.z = sz * (1.0f / FUSE_K);
    r.w = sw * (1.0f / FUSE_K);
    out4[gid] = r;
}

extern "C" void kernel_launch(void* const* d_in, const int* in_sizes, int n_in,
                              void* d_out, int out_size, void* d_ws, size_t ws_size,
                              hipStream_t stream) {
    // d_in[0] = invoxel_xyz (unused by the reference)
    // d_in[1] = invoxel_map (int32), in_sizes[1] = N * FUSE_K
    // d_in[2] = src_feat    (float32, M x 16)
    const int*    invoxel_map = (const int*)d_in[1];
    const float4* src_feat4   = (const float4*)d_in[2];
    float4*       out4        = (float4*)d_out;

    int N = in_sizes[1] / FUSE_K;
    int total = N * 4;
    int block = 256;
    int grid = (total + block - 1) / block;

    VoxelPooling_kernel<<<grid, block, 0, stream>>>(invoxel_map, src_feat4, out4, N);
}